// Round 9
// baseline (139.754 us; speedup 1.0000x reference)
//
#include <hip/hip_runtime.h>
#include <hip/hip_bf16.h>

// Fused 2-layer SimpleRNN, fp16 MFMA (16x16x32), fp32 accumulate.
// Round 23: ONE-DIRECTIONAL 2-WAVE PIPELINE (A -> B, no feedback edge).
//   R22 post-mortem (WIN, 50.5 us): per-MFMA wave-blocking ~43 cyc is the
//   wall — iter 1520 = 378 MFMA-busy + 239 VALU + ~900 idle (blocking +
//   gather). A single wave cannot fill its own MFMA shadow; the only move
//   is FEWER MFMAs on the critical wave.
//   Split: ax(t) = b2 + Wx2^T h1(t) depends only on h1 -> layer-2 needs
//   ONLY ax. Wave A: h1 chain + Wx2 (16 MFMA + tanh1 + gather, ~1050/iter,
//   never waits). Wave B: Wh2 chain C-init=ax (8 MFMA + tanh2 + head,
//   ~550/iter, sleep-polls with huge slack — off critical path).
//   Handoff: 4-slot LDS FIFO of ax (fp32, XOR-swizzled b128), relaxed
//   atomic flags. DS in-order per wave => producer flag needs no waitcnt;
//   consumer drains lgkmcnt before signaling. Accumulation order
//   bit-identical to R22: (b2+Wx2k0+Wx2k1)[A] then (+Wh2k0+Wh2k1)[B].
// Grid 1024 x 128 threads (A+B) = 2048 waves = 2 waves/SIMD.

#define BATCH 16384
#define SEQ   80
#define EMBED 100
#define UNITS 64
#define ROWS  16
#define VOCAB 10000

typedef __attribute__((ext_vector_type(8))) _Float16 f16x8;
typedef __attribute__((ext_vector_type(4))) float f32x4;
typedef __attribute__((ext_vector_type(2))) float f32x2;
typedef __attribute__((ext_vector_type(4))) int   i32x4;
typedef __attribute__((ext_vector_type(2))) int   i32x2;

// packed half2 in the builtin's own type (keeps clang type-happy)
using h2t = decltype(__builtin_amdgcn_cvt_pkrtz(0.f, 0.f));

// scalar fp32 tanh for the once-only epilogue
static __device__ __forceinline__ f32x2 tanh2(f32x2 x) {
    f32x2 u = x * x;
    f32x2 w = x * u;
    f32x2 p = u * 0.13333333f + (-0.33333333f);
    return w * p + x;
}

static __device__ __forceinline__ f16x8 ash(i32x4 v) {
    return __builtin_bit_cast(f16x8, v);
}

// xp[v][u] = b1[u] + sum_k emb[v][k] * Wx1[k][u]   (fp32, exact)
__global__ __launch_bounds__(256) void xp_prep(const float* __restrict__ emb,
                                               const float* __restrict__ Wx1,
                                               const float* __restrict__ b1,
                                               float* __restrict__ xp) {
    const int v = blockIdx.x * 4 + (threadIdx.x >> 6);
    const int u = threadIdx.x & 63;
    const float* er = emb + (size_t)v * EMBED;
    const float* wc = Wx1 + u;
    float acc = b1[u];
#pragma unroll 5
    for (int k4 = 0; k4 < EMBED / 4; ++k4) {
        f32x4 e = *reinterpret_cast<const f32x4*>(er + k4 * 4);
        acc += e[0] * wc[(k4 * 4 + 0) * UNITS];
        acc += e[1] * wc[(k4 * 4 + 1) * UNITS];
        acc += e[2] * wc[(k4 * 4 + 2) * UNITS];
        acc += e[3] * wc[(k4 * 4 + 3) * UNITS];
    }
    xp[(size_t)v * UNITS + u] = acc;
}

__global__ __launch_bounds__(128)
void rnn_fused(const int* __restrict__ tokens,
               const float* __restrict__ xpT,
               const float* __restrict__ Wh1,
               const float* __restrict__ Wx2,
               const float* __restrict__ Wh2,
               const float* __restrict__ b2,
               const float* __restrict__ Wd,
               const float* __restrict__ bd,
               float* __restrict__ out)
{
    __shared__ int   tokL[ROWS][SEQ + 1];
    __shared__ float axS[4 * 64 * 16];   // 4-slot FIFO of ax C-frags, 16 KB
    __shared__ int   prodF, consF;

    const int tid  = threadIdx.x;
    const int wv   = tid >> 6;       // 0 = A (producer), 1 = B (consumer)
    const int lane = tid & 63;
    const int c    = lane & 15;      // batch col (B/C n-index)
    const int q    = lane >> 4;      // quad
    const int rowBase = blockIdx.x * ROWS;

    if (tid == 0) { prodF = 0; consF = 0; }
    for (int i = tid; i < ROWS * SEQ; i += 128) {
        int r = i / SEQ, tt = i - r * SEQ;
        tokL[r][tt] = tokens[rowBase * SEQ + i];
    }
    __syncthreads();   // only barrier in the kernel

    // XOR-swizzled FIFO addressing: per (lane) the 4 mt-frags are permuted
    // so consecutive lanes' b128 ops spread across banks. Same map on both
    // sides; bijective in mt.
    auto axIdx = [&](int slot, int mt) {
        return slot * 1024 + lane * 16 + ((mt ^ ((lane >> 1) & 3)) << 2);
    };

    // permuted-k weight A-frag loader: slot (kt,q,j) <-> u = 32kt+16(j>>2)+4q+(j&3)
    auto loadW = [&](const float* W, f16x8 (&dst)[2][4]) {
#pragma unroll
        for (int kt = 0; kt < 2; ++kt)
#pragma unroll
            for (int mt = 0; mt < 4; ++mt) {
                f16x8 v;
#pragma unroll
                for (int j = 0; j < 8; ++j) {
                    int u = kt * 32 + ((j >> 2) << 4) + q * 4 + (j & 3);
                    v[j] = (_Float16)W[u * UNITS + mt * 16 + c];   // RNE
                }
                dst[kt][mt] = v;
            }
    };

    // packed-half tanh (Taylor-5) + fp16 pack, shared by both waves
    const h2t kC1h = __builtin_amdgcn_cvt_pkrtz( 0.13333333f,  0.13333333f);
    const h2t kC0h = __builtin_amdgcn_cvt_pkrtz(-0.33333333f, -0.33333333f);
    auto tanh_pack4 = [&](f32x4 v) -> i32x2 {
        h2t lo = __builtin_amdgcn_cvt_pkrtz(v[0], v[1]);
        h2t hi = __builtin_amdgcn_cvt_pkrtz(v[2], v[3]);
        h2t ulo = lo * lo,          uhi = hi * hi;
        h2t wlo = ulo * lo,         whi = uhi * hi;
        h2t plo = ulo * kC1h + kC0h, phi = uhi * kC1h + kC0h;
        h2t rlo = wlo * plo + lo,   rhi = whi * phi + hi;
        i32x2 r;
        r[0] = __builtin_bit_cast(int, rlo);
        r[1] = __builtin_bit_cast(int, rhi);
        return r;
    };
    auto tanhP = [&](f32x4 (&a)[4], i32x4 (&h)[2]) {
        i32x2 p0 = tanh_pack4(a[0]), p1 = tanh_pack4(a[1]);
        i32x2 p2 = tanh_pack4(a[2]), p3 = tanh_pack4(a[3]);
        h[0] = (i32x4){p0[0], p0[1], p1[0], p1[1]};
        h[1] = (i32x4){p2[0], p2[1], p3[0], p3[1]};
    };

    if (wv == 0) {
        // ================= Wave A: h1 chain + Wx2 projection =================
        f16x8 awh1[2][4], awx2[2][4];
        loadW(Wh1, awh1);
        loadW(Wx2, awx2);

        f32x4 b2C[4];
#pragma unroll
        for (int mt = 0; mt < 4; ++mt)
#pragma unroll
            for (int r = 0; r < 4; ++r)
                b2C[mt][r] = b2[mt * 16 + q * 4 + r];

        const int* tokC = &tokL[c][0];
        auto gatherXP = [&](int tk, f32x4 (&dst)[4]) {
            const float* p = xpT + (unsigned)tk * UNITS + q * 4;
            dst[0] = *reinterpret_cast<const f32x4*>(p);
            dst[1] = *reinterpret_cast<const f32x4*>(p + 16);
            dst[2] = *reinterpret_cast<const f32x4*>(p + 32);
            dst[3] = *reinterpret_cast<const f32x4*>(p + 48);
        };

        i32x4 h1[2] = {(i32x4){0,0,0,0}, (i32x4){0,0,0,0}};
        f32x4 xp0[4], xp1[4];
        gatherXP(tokC[0], xp0);
        gatherXP(tokC[1], xp1);

        int consNow = 0;

        // body(t), t in [1,79]:
        //   aL1 = xp(t) + Wh1^T h1(t-1) -> h1(t)
        //   ax(t-1) = b2 + Wx2^T h1(t-1) -> FIFO slot (t-1)&3
        auto body = [&](int t, f32x4 (&xpS)[4], bool pre, int tp) {
            // early, non-blocking: refresh back-pressure view (use ~800 cyc later)
            consNow = __hip_atomic_load(&consF, __ATOMIC_RELAXED,
                                        __HIP_MEMORY_SCOPE_WORKGROUP);
            f32x4 aL1[4], ax[4];
#pragma unroll
            for (int mt = 0; mt < 4; ++mt)
                aL1[mt] = __builtin_amdgcn_mfma_f32_16x16x32_f16(awh1[0][mt], ash(h1[0]), xpS[mt], 0, 0, 0);
#pragma unroll
            for (int mt = 0; mt < 4; ++mt)
                ax[mt] = __builtin_amdgcn_mfma_f32_16x16x32_f16(awx2[0][mt], ash(h1[0]), b2C[mt], 0, 0, 0);
#pragma unroll
            for (int mt = 0; mt < 4; ++mt)
                aL1[mt] = __builtin_amdgcn_mfma_f32_16x16x32_f16(awh1[1][mt], ash(h1[1]), aL1[mt], 0, 0, 0);
#pragma unroll
            for (int mt = 0; mt < 4; ++mt)
                ax[mt] = __builtin_amdgcn_mfma_f32_16x16x32_f16(awx2[1][mt], ash(h1[1]), ax[mt], 0, 0, 0);
            if (pre) gatherXP(tp, xpS);
            tanhP(aL1, h1);   // h1(t)
            // back-pressure: slot (t-1)&3 last held item t-5; need consF >= t-4.
            // B runs 2x faster, so this never loops in steady state.
            if (t >= 5) {
                while (consNow < t - 4) {
                    __builtin_amdgcn_s_sleep(1);
                    consNow = __hip_atomic_load(&consF, __ATOMIC_RELAXED,
                                                __HIP_MEMORY_SCOPE_WORKGROUP);
                }
            }
            const int slot = (t - 1) & 3;
#pragma unroll
            for (int mt = 0; mt < 4; ++mt)
                *reinterpret_cast<f32x4*>(&axS[axIdx(slot, mt)]) = ax[mt];
            asm volatile("" ::: "memory");   // pin order: data writes then flag
            // DS ops complete in-order per wave: flag visible => data visible.
            __hip_atomic_store(&prodF, t, __ATOMIC_RELAXED,
                               __HIP_MEMORY_SCOPE_WORKGROUP);
        };

        // ---- t = 0 peeled: h1(0) = tanh(xp(0)) (h1-in = 0) ----
        {
            f32x4 aL1[4];
#pragma unroll
            for (int mt = 0; mt < 4; ++mt)
                aL1[mt] = __builtin_amdgcn_mfma_f32_16x16x32_f16(awh1[0][mt], ash(h1[0]), xp0[mt], 0, 0, 0);
#pragma unroll
            for (int mt = 0; mt < 4; ++mt)
                aL1[mt] = __builtin_amdgcn_mfma_f32_16x16x32_f16(awh1[1][mt], ash(h1[1]), aL1[mt], 0, 0, 0);
            gatherXP(tokC[2], xp0);
            tanhP(aL1, h1);   // h1(0)
        }

        // ---- t = 1..76 in parity pairs (xp(t) lives in buffer t&1) ----
#pragma unroll 1
        for (int tt = 1; tt <= 75; tt += 2) {
            body(tt,     xp1, true, tokC[tt + 2]);
            body(tt + 1, xp0, true, tokC[tt + 3]);
        }
        body(77, xp1, true, tokC[79]);
        body(78, xp0, false, 0);
        body(79, xp1, false, 0);   // h1(79); ax(78) sent

        // ---- tail: ax(79) = b2 + Wx2^T h1(79) ----
        {
            while (consNow < 76) {
                __builtin_amdgcn_s_sleep(1);
                consNow = __hip_atomic_load(&consF, __ATOMIC_RELAXED,
                                            __HIP_MEMORY_SCOPE_WORKGROUP);
            }
            f32x4 ax[4];
#pragma unroll
            for (int mt = 0; mt < 4; ++mt)
                ax[mt] = __builtin_amdgcn_mfma_f32_16x16x32_f16(awx2[0][mt], ash(h1[0]), b2C[mt], 0, 0, 0);
#pragma unroll
            for (int mt = 0; mt < 4; ++mt)
                ax[mt] = __builtin_amdgcn_mfma_f32_16x16x32_f16(awx2[1][mt], ash(h1[1]), ax[mt], 0, 0, 0);
            const int slot = 79 & 3;
#pragma unroll
            for (int mt = 0; mt < 4; ++mt)
                *reinterpret_cast<f32x4*>(&axS[axIdx(slot, mt)]) = ax[mt];
            asm volatile("" ::: "memory");
            __hip_atomic_store(&prodF, 80, __ATOMIC_RELAXED,
                               __HIP_MEMORY_SCOPE_WORKGROUP);
        }

    } else {
        // ================= Wave B: h2 chain (C-init = ax) + head =================
        f16x8 awh2[2][4];
        loadW(Wh2, awh2);
        f32x4 wdC[4];
#pragma unroll
        for (int mt = 0; mt < 4; ++mt)
#pragma unroll
            for (int r = 0; r < 4; ++r)
                wdC[mt][r] = Wd[mt * 16 + q * 4 + r];
        const float bdv = bd[0];

        i32x4 h2s[2] = {(i32x4){0,0,0,0}, (i32x4){0,0,0,0}};

#pragma unroll 1
        for (int t = 0; t < SEQ; ++t) {
            while (__hip_atomic_load(&prodF, __ATOMIC_RELAXED,
                                     __HIP_MEMORY_SCOPE_WORKGROUP) < t + 1)
                __builtin_amdgcn_s_sleep(1);
            asm volatile("" ::: "memory");   // reads stay below the poll
            f32x4 xc[4];
            const int slot = t & 3;
#pragma unroll
            for (int mt = 0; mt < 4; ++mt)
                xc[mt] = *reinterpret_cast<const f32x4*>(&axS[axIdx(slot, mt)]);
            asm volatile("s_waitcnt lgkmcnt(0)" ::: "memory");  // reads landed
            __hip_atomic_store(&consF, t + 1, __ATOMIC_RELAXED,
                               __HIP_MEMORY_SCOPE_WORKGROUP);
            f32x4 a2[4];
#pragma unroll
            for (int mt = 0; mt < 4; ++mt)
                a2[mt] = __builtin_amdgcn_mfma_f32_16x16x32_f16(awh2[0][mt], ash(h2s[0]), xc[mt], 0, 0, 0);
#pragma unroll
            for (int mt = 0; mt < 4; ++mt)
                a2[mt] = __builtin_amdgcn_mfma_f32_16x16x32_f16(awh2[1][mt], ash(h2s[1]), a2[mt], 0, 0, 0);
            if (t < SEQ - 1) {
                tanhP(a2, h2s);   // h2(t)
            } else {
                // ---- head on h2(79) pre-tanh, all fp32 ----
                float p = 0.f;
#pragma unroll
                for (int mt = 0; mt < 4; ++mt) {
                    f32x2 lo = tanh2((f32x2){a2[mt][0], a2[mt][1]});
                    f32x2 hi = tanh2((f32x2){a2[mt][2], a2[mt][3]});
                    p += lo[0] * wdC[mt][0] + lo[1] * wdC[mt][1]
                       + hi[0] * wdC[mt][2] + hi[1] * wdC[mt][3];
                }
                p += __shfl_xor(p, 16);
                p += __shfl_xor(p, 32);
                if (q == 0) {
                    float x = p + bdv;
                    out[rowBase + c] = __builtin_amdgcn_rcpf(1.0f + __expf(-x));
                }
            }
        }
    }
}

extern "C" void kernel_launch(void* const* d_in, const int* in_sizes, int n_in,
                              void* d_out, int out_size, void* d_ws, size_t ws_size,
                              hipStream_t stream) {
    const int*   tokens = (const int*)  d_in[0];
    const float* emb    = (const float*)d_in[1];
    const float* Wx1    = (const float*)d_in[2];
    const float* Wh1    = (const float*)d_in[3];
    const float* b1     = (const float*)d_in[4];
    const float* Wx2    = (const float*)d_in[5];
    const float* Wh2    = (const float*)d_in[6];
    const float* b2     = (const float*)d_in[7];
    const float* Wd     = (const float*)d_in[8];
    const float* bd     = (const float*)d_in[9];
    float* out = (float*)d_out;

    // xp = emb@Wx1 + b1 (2.56 MB in d_ws; ws has held >= this in all rounds)
    float* xp = (float*)d_ws;
    xp_prep<<<dim3(VOCAB / 4), dim3(256), 0, stream>>>(emb, Wx1, b1, xp);

    dim3 grid(BATCH / ROWS);  // 1024 blocks x 2 waves = 2 waves/SIMD
    dim3 block(128);
    rnn_fused<<<grid, block, 0, stream>>>(tokens, xp, Wh1, Wx2, Wh2, b2, Wd, bd, out);
}